// Round 18
// baseline (402.264 us; speedup 1.0000x reference)
//
#include <hip/hip_runtime.h>
#include <hip/hip_bf16.h>
#include <cstdint>
#include <cstddef>

constexpr int SEQ = 8192;
constexpr int DIM = 1024;
constexpr int BAND = 2048;

typedef __attribute__((ext_vector_type(8))) short short8;   // bf16x8 MFMA frag
typedef __attribute__((ext_vector_type(4))) float f32x4;    // fp32x4 acc frag
typedef __attribute__((ext_vector_type(4))) unsigned short us4;

#define MFMA_BF16 __builtin_amdgcn_mfma_f32_16x16x32_bf16

static __device__ __forceinline__ unsigned short f2bf(float f) {
    uint32_t u = __builtin_bit_cast(uint32_t, f);
    u += 0x7FFFu + ((u >> 16) & 1u);      // round-to-nearest-even
    return (unsigned short)(u >> 16);
}
static __device__ __forceinline__ float bf2f(unsigned short h) {
    uint32_t u = ((uint32_t)h) << 16;
    return __builtin_bit_cast(float, u);
}
static __device__ __forceinline__ int r64(int x) {          // round to mult of 64
    return ((x + 32) >> 6) << 6;
}

#define GLOAD16(gp, lp) __builtin_amdgcn_global_load_lds(                      \
    (const __attribute__((address_space(1))) void*)(gp),                       \
    (__attribute__((address_space(3))) void*)(lp), 16, 0, 0)

// ---------------------------------------------------------------------------
// GEMM: C[M,N] = A[M,K] @ Bt[N,K]^T   (A, Bt bf16 row-major; Bt is B^T)
// BM=256, BN=128, BK=64. 512 threads = 8 waves (4M x 2N wave grid; per-wave
// inner loop identical to the r12-verified optimum). Taller A-tile cuts
// staged bytes/FLOP 15.5 -> 11.4 B/KFLOP and halves barriers/FLOP (the
// structure is staging-bound at ~10 TB/s chip-wide — r12/r17 measured).
// Single-buffered 2-barrier K-loop; XOR slot-swizzle (0 bank conflicts);
// bijective chunked XCD swizzle, y-fastest flatten. LDS 48 KB.
// OM: 0=bf16 C[M,N]; 2=fp32 C[M,N]; 3=bf16 partial at Cp+z*M*N (split-K);
//     4=QKV-routed (col<1024 Q, <2048 K, else V^T at +2*SEQ*DIM);
//     5=QK^T fused: P=exp(masked(s*scale)) bf16 + row-sum partials
//       Sp[row*128 + bxi*2+wc] (row-major; r16's col-major was +60us).
//       256-row blocks write masked zeros for ALL cols < rowBase+bm+256,
//       matching PV's BM=256 Keff exactly (no stale reads).
// SPLITK: even per-row split — k range [r64(z*Keff/NS), r64((z+1)*Keff/NS)).
// ---------------------------------------------------------------------------
template<int OM, bool CAUSAL, bool KCAP, bool SPLITK>
__global__ __launch_bounds__(512, 4)
void gemm_bt(const unsigned short* __restrict__ A,
             const unsigned short* __restrict__ Bt,
             void* __restrict__ Cp,
             int M, int N, int K, float scale, int rowBase, int NS,
             float* __restrict__ Sp)
{
    constexpr int BM = 256, BK = 64, BN = 128;
    constexpr int NF = 4;                 // b-frags per wave (BN/2/16)
    __shared__ __align__(16) unsigned short As[BM * BK];   // 32 KB
    __shared__ __align__(16) unsigned short Bs[BN * BK];   // 16 KB

    const int t = threadIdx.x;
    const int lane = t & 63, w = t >> 6;  // 8 waves
    const int wr = w >> 1, wc = w & 1;    // 4M x 2N
    const int ln15 = lane & 15, hi = lane >> 4;

    // ---- chunked-bijective XCD swizzle, y-fastest flatten
    const int gx = gridDim.x, gy = gridDim.y;
    const int nwg = gx * gy * gridDim.z;
    const int orig = blockIdx.y + gy * (blockIdx.x + gx * blockIdx.z);
    const int q = nwg >> 3, r8 = nwg & 7;
    const int xcd = orig & 7, idx = orig >> 3;
    const int wg = (xcd < r8 ? xcd * (q + 1)
                             : r8 * (q + 1) + (xcd - r8) * q) + idx;
    const int byi = wg % gy, tmpw = wg / gy;
    const int bxi = tmpw % gx, bzi = tmpw / gx;

    const int bm = byi * BM, bn = bxi * BN;

    if (CAUSAL && bn > rowBase + bm + (BM - 1)) return;   // fully-masked tile
    int Keff = K;
    if (KCAP) { int kc = rowBase + bm + BM; Keff = kc < K ? kc : K; }
    int kbeg = 0, kend = Keff;
    if (SPLITK) {
        kbeg = r64(bzi * Keff / NS);
        int ke = r64((bzi + 1) * Keff / NS);
        kend = ke < Keff ? ke : Keff;
        if (kbeg >= kend) return;          // empty slice (small Keff rows)
    }

    f32x4 acc[4][NF] = {};

    for (int k0 = kbeg; k0 < kend; k0 += BK) {
        // ---- stage tiles: A 2048 chunks (4/thread), B 1024 (2/thread)
        #pragma unroll
        for (int i = 0; i < 4; ++i) {
            int c = t + 512 * i;
            int r = c >> 3, qq = (c & 7) ^ (r & 7);       // pre-swizzled src
            GLOAD16(A + (size_t)(bm + r) * K + k0 + qq * 8, As + c * 8);
        }
        #pragma unroll
        for (int i = 0; i < 2; ++i) {
            int c = t + 512 * i;
            int r = c >> 3, qq = (c & 7) ^ (r & 7);
            GLOAD16(Bt + (size_t)(bn + r) * K + k0 + qq * 8, Bs + c * 8);
        }
        __syncthreads();                   // drains loads, publishes tile

        #pragma unroll
        for (int kk = 0; kk < 2; ++kk) {
            short8 a[4], b[NF];
            #pragma unroll
            for (int m = 0; m < 4; ++m) {
                int r = wr * 64 + m * 16 + ln15;
                int s = (kk * 4 + hi) ^ (r & 7);          // swizzled read
                a[m] = *(const short8*)(As + r * 64 + s * 8);
            }
            #pragma unroll
            for (int n = 0; n < NF; ++n) {
                int r = wc * 64 + n * 16 + ln15;
                int s = (kk * 4 + hi) ^ (r & 7);
                b[n] = *(const short8*)(Bs + r * 64 + s * 8);
            }
            __builtin_amdgcn_s_setprio(1);
            #pragma unroll
            for (int m = 0; m < 4; ++m)
                #pragma unroll
                for (int n = 0; n < NF; ++n)
                    acc[m][n] = MFMA_BF16(a[m], b[n], acc[m][n], 0, 0, 0);
            __builtin_amdgcn_s_setprio(0);
        }
        __syncthreads();                   // all waves done reading the tile
    }

    // ---- epilogue: C/D layout col = lane&15, row = (lane>>4)*4 + j
    if (OM == 5) {
        float psum[4][4];
        #pragma unroll
        for (int m = 0; m < 4; ++m)
            #pragma unroll
            for (int j = 0; j < 4; ++j) {
                int row = bm + wr * 64 + m * 16 + hi * 4 + j;
                int grow = rowBase + row;
                float s = 0.f;
                #pragma unroll
                for (int n = 0; n < NF; ++n) {
                    int col = bn + wc * 64 + n * 16 + ln15;
                    float p = (col <= grow)
                        ? __expf(acc[m][n][j] * scale) : 0.f;
                    ((unsigned short*)Cp)[(size_t)row * N + col] = f2bf(p);
                    s += p;
                }
                psum[m][j] = s;
            }
        #pragma unroll
        for (int off = 1; off < 16; off <<= 1)
            #pragma unroll
            for (int m = 0; m < 4; ++m)
                #pragma unroll
                for (int j = 0; j < 4; ++j)
                    psum[m][j] += __shfl_xor(psum[m][j], off, 64);
        if (ln15 == 0) {
            const int ci = bxi * 2 + wc;           // row-major Sp[row][128]
            #pragma unroll
            for (int m = 0; m < 4; ++m)
                #pragma unroll
                for (int j = 0; j < 4; ++j)
                    Sp[(size_t)(bm + wr * 64 + m * 16 + hi * 4 + j) * 128 + ci]
                        = psum[m][j];
        }
        return;
    }
    #pragma unroll
    for (int m = 0; m < 4; ++m)
        #pragma unroll
        for (int n = 0; n < NF; ++n)
            #pragma unroll
            for (int j = 0; j < 4; ++j) {
                int row = bm + wr * 64 + m * 16 + hi * 4 + j;
                int col = bn + wc * 64 + n * 16 + ln15;
                float v = acc[m][n][j] * scale;
                if (OM == 0)
                    ((unsigned short*)Cp)[(size_t)row * N + col] = f2bf(v);
                else if (OM == 2)
                    ((float*)Cp)[(size_t)row * N + col] = v;
                else if (OM == 3)
                    ((unsigned short*)Cp + (size_t)bzi * M * N)
                        [(size_t)row * N + col] = f2bf(v);
                else {                       // OM == 4: QKV routing
                    unsigned short* qb = (unsigned short*)Cp;
                    if (col < DIM)
                        qb[(size_t)row * DIM + col] = f2bf(v);
                    else if (col < 2 * DIM)
                        (qb + (size_t)SEQ * DIM)
                            [(size_t)row * DIM + (col - DIM)] = f2bf(v);
                    else
                        (qb + (size_t)2 * SEQ * DIM)
                            [(size_t)(col - 2 * DIM) * SEQ + row] = f2bf(v);
                }
            }
}

// ---------------------------------------------------------------------------
// Split-K reduction: cooperative rowsum from row-major Sp (128 threads/row),
// then sum bf16 partial slices, divide, SiLU, bf16 -> out (band rows).
// keb uses the PV kernel's 256-ROW K-cap granularity.
// ---------------------------------------------------------------------------
__global__ __launch_bounds__(256)
void reduce_silu(const unsigned short* __restrict__ part,
                 const float* __restrict__ Sp,
                 unsigned short* __restrict__ out, int ns, int rowBase)
{
    __shared__ float red[4];
    const int t = threadIdx.x, lane = t & 63, w = t >> 6;
    const size_t idx = ((size_t)blockIdx.x * 256 + t) * 8;
    const int r = (int)(idx >> 10);                 // band-local row
    int keb = rowBase + ((r >> 8) << 8) + 256;      // Keff of r's PV block-row
    if (keb > SEQ) keb = SEQ;

    // ---- cooperative rowsum: threads t>>7 pick the block's 2 rows
    {
        const int rloc = blockIdx.x * 2 + (t >> 7);
        const int seg = t & 127;
        const int nct = 2 * (((rowBase + rloc) >> 7) + 1);  // live tile-halves
        float val = (seg < nct) ? Sp[(size_t)rloc * 128 + seg] : 0.f;
        #pragma unroll
        for (int off = 1; off < 64; off <<= 1)
            val += __shfl_xor(val, off, 64);
        if (lane == 0) red[w] = val;
    }
    __syncthreads();
    const float inv = 1.0f /
        ((t < 128) ? (red[0] + red[1]) : (red[2] + red[3]));

    float s[8] = {};
    for (int z = 0; z < ns; ++z) {
        int b0 = r64(z * keb / ns);
        int b1 = r64((z + 1) * keb / ns);
        if (b1 > keb) b1 = keb;
        if (b1 > b0) {
            short8 p = *(const short8*)(part + (size_t)z * (BAND * DIM) + idx);
            #pragma unroll
            for (int j = 0; j < 8; ++j) s[j] += bf2f((unsigned short)p[j]);
        }
    }
    short8 o;
    #pragma unroll
    for (int j = 0; j < 8; ++j) {
        float v = s[j] * inv;
        o[j] = (short)f2bf(v / (1.0f + __expf(-v)));
    }
    *(short8*)(out + idx) = o;
}

// ---------------------------------------------------------------------------
__global__ __launch_bounds__(256)
void cvt_bf16(const float* __restrict__ X, unsigned short* __restrict__ Y)
{
    int i = (blockIdx.x * 256 + threadIdx.x) * 8;
    f32x4 v0 = *(const f32x4*)(X + i);
    f32x4 v1 = *(const f32x4*)(X + i + 4);
    short8 o = { (short)f2bf(v0[0]), (short)f2bf(v0[1]),
                 (short)f2bf(v0[2]), (short)f2bf(v0[3]),
                 (short)f2bf(v1[0]), (short)f2bf(v1[1]),
                 (short)f2bf(v1[2]), (short)f2bf(v1[3]) };
    *(short8*)(Y + i) = o;
}

// ---------------------------------------------------------------------------
__global__ __launch_bounds__(256)
void twT(const float* __restrict__ W, unsigned short* __restrict__ WT)
{
    __shared__ float tile[64][65];
    const int bx = blockIdx.x * 64, by = blockIdx.y * 64;
    const int t = threadIdx.x, rr = t >> 4, c4 = (t & 15) * 4;
    #pragma unroll
    for (int i = 0; i < 4; ++i) {
        int r = rr + i * 16;
        f32x4 v = *(const f32x4*)(W + (size_t)(by + r) * DIM + bx + c4);
        tile[r][c4 + 0] = v[0]; tile[r][c4 + 1] = v[1];
        tile[r][c4 + 2] = v[2]; tile[r][c4 + 3] = v[3];
    }
    __syncthreads();
    #pragma unroll
    for (int i = 0; i < 4; ++i) {
        int r = rr + i * 16;                           // WT row = bx + r
        us4 o = { f2bf(tile[c4 + 0][r]), f2bf(tile[c4 + 1][r]),
                  f2bf(tile[c4 + 2][r]), f2bf(tile[c4 + 3][r]) };
        *(us4*)(WT + (size_t)(bx + r) * DIM + by + c4) = o;
    }
}

// ---------------------------------------------------------------------------
extern "C" void kernel_launch(void* const* d_in, const int* in_sizes, int n_in,
                              void* d_out, int out_size, void* d_ws, size_t ws_size,
                              hipStream_t stream)
{
    const float* x   = (const float*)d_in[0];
    const float* wq  = (const float*)d_in[1];
    const float* wk  = (const float*)d_in[2];
    const float* wv1 = (const float*)d_in[3];
    const float* wv2 = (const float*)d_in[4];

    // ws: Q/H | K (later wv2T) | V^T | bf16 split-K partials | Sp rowsums
    const size_t E = (size_t)SEQ * DIM;              // 16 MB bf16 each
    unsigned short* qbuf  = (unsigned short*)d_ws;   // [S,D]
    unsigned short* kbuf  = qbuf + E;                // [S,D]
    unsigned short* vtbuf = kbuf + E;                // [D,S]
    unsigned short* part  = vtbuf + E;               // NS x [BAND,D] bf16
    float* Sp = (float*)(part + 4 * (size_t)BAND * DIM);  // [BAND][128] f32
    const size_t PBUF = (size_t)BAND * DIM * sizeof(unsigned short);
    int nsplit = 1;
    if (ws_size >= 3 * E * sizeof(unsigned short) + 4 * PBUF
                   + 128 * (size_t)BAND * sizeof(float)) nsplit = 4;

    // d_out (32 MB) staging: xb (16 MB) + wqT|wkT|wv1T (6 MB), then S bands.
    unsigned short* xb    = (unsigned short*)d_out;
    unsigned short* wqkv  = xb + E;                  // [3072][1024]
    unsigned short* Sband = (unsigned short*)d_out;  // [BAND][SEQ] = 32 MB

    dim3 tg(16, 16);
    cvt_bf16<<<SEQ * DIM / 2048, 256, 0, stream>>>(x, xb);
    twT<<<tg, 256, 0, stream>>>(wq,  wqkv);
    twT<<<tg, 256, 0, stream>>>(wk,  wqkv + DIM * DIM);
    twT<<<tg, 256, 0, stream>>>(wv1, wqkv + 2 * DIM * DIM);

    // Merged QKV projection: [S,1024] @ [3072,1024]^T, routed epilogue.
    gemm_bt<4,false,false,false><<<dim3(3 * DIM / 128, SEQ / 256), 512, 0, stream>>>(
        xb, wqkv, qbuf, SEQ, 3 * DIM, DIM, 1.0f, 0, 0, nullptr);

    for (int b = 0; b < 4; ++b) {
        const int rb = b * BAND;
        const int ncol = (rb + BAND) / 128;        // prune all-masked columns
        dim3 gq(ncol, BAND / 256);
        // QK^T with fused exp + row-sum partials (no separate softmax pass)
        gemm_bt<5,true,false,false><<<gq, 512, 0, stream>>>(
            qbuf + (size_t)rb * DIM, kbuf, Sband, BAND, SEQ, DIM,
            0.03125f, rb, 0, Sp);
        if (b == 3)  // K no longer needed: stage wv2^T into kbuf
            twT<<<tg, 256, 0, stream>>>(wv2, kbuf);
        dim3 gpv(DIM / 128, BAND / 256, nsplit);
        gemm_bt<3,false,true,true><<<gpv, 512, 0, stream>>>(
            Sband, vtbuf, part, BAND, DIM, SEQ, 1.0f, rb, nsplit, nullptr);
        reduce_silu<<<BAND * DIM / 2048, 256, 0, stream>>>(
            part, Sp, qbuf + (size_t)rb * DIM, nsplit, rb);
    }

    // Output projection: silu(hidden) @ wv2 -> fp32 d_out.
    gemm_bt<2,false,false,false><<<dim3(DIM / 128, SEQ / 256), 512, 0, stream>>>(
        qbuf, kbuf, d_out, SEQ, DIM, DIM, 1.0f, 0, 0, nullptr);
}

// Round 19
// 367.995 us; speedup vs baseline: 1.0931x; 1.0931x over previous
//
#include <hip/hip_runtime.h>
#include <hip/hip_bf16.h>
#include <cstdint>
#include <cstddef>

constexpr int SEQ = 8192;
constexpr int DIM = 1024;
constexpr int BAND = 2048;

typedef __attribute__((ext_vector_type(8))) short short8;   // bf16x8 MFMA frag
typedef __attribute__((ext_vector_type(4))) float f32x4;    // fp32x4 acc frag
typedef __attribute__((ext_vector_type(4))) unsigned short us4;

#define MFMA_BF16 __builtin_amdgcn_mfma_f32_16x16x32_bf16

static __device__ __forceinline__ unsigned short f2bf(float f) {
    uint32_t u = __builtin_bit_cast(uint32_t, f);
    u += 0x7FFFu + ((u >> 16) & 1u);      // round-to-nearest-even
    return (unsigned short)(u >> 16);
}
static __device__ __forceinline__ float bf2f(unsigned short h) {
    uint32_t u = ((uint32_t)h) << 16;
    return __builtin_bit_cast(float, u);
}
static __device__ __forceinline__ int r64(int x) {          // round to mult of 64
    return ((x + 32) >> 6) << 6;
}

#define GLOAD16(gp, lp) __builtin_amdgcn_global_load_lds(                      \
    (const __attribute__((address_space(1))) void*)(gp),                       \
    (__attribute__((address_space(3))) void*)(lp), 16, 0, 0)

// ---------------------------------------------------------------------------
// GEMM: C[M,N] = A[M,K] @ Bt[N,K]^T   (A, Bt bf16 row-major; Bt is B^T)
// BM=128, BK=64, BN=128. 256 threads = 4 waves. m97-style single-buffered
// 2-barrier K-loop — r12/r17-verified optimum (762 TF; staging-bound;
// deeper pipelining neutral r10-r11; BM=256 regressed r18: fewer, bigger
// barrier groups expose stage latency — this structure needs MANY small
// independent blocks). XOR slot-swizzle (0 bank conflicts); bijective
// chunked XCD swizzle, y-fastest flatten.
// OM: 0=bf16 C[M,N]; 2=fp32 C[M,N]; 3=bf16 partial at Cp+z*M*N (split-K);
//     4=QKV-routed (col<1024 Q, <2048 K, else V^T at +2*SEQ*DIM);
//     5=QK^T fused: P=exp(masked(s*scale)) bf16 + row-sum partials
//       Sp[row*128 + bxi*2+wc] (row-major; col-major was +60us r16).
// SPLITK: even per-row split — k range [r64(z*Keff/NS), r64((z+1)*Keff/NS)).
// ---------------------------------------------------------------------------
template<int OM, bool CAUSAL, bool KCAP, bool SPLITK>
__global__ __launch_bounds__(256, 4)
void gemm_bt(const unsigned short* __restrict__ A,
             const unsigned short* __restrict__ Bt,
             void* __restrict__ Cp,
             int M, int N, int K, float scale, int rowBase, int NS,
             float* __restrict__ Sp)
{
    constexpr int BM = 128, BK = 64, BN = 128;
    constexpr int NF = BN / 32;           // 4 b-frags per wave
    __shared__ __align__(16) unsigned short As[BM * BK];   // 16 KB
    __shared__ __align__(16) unsigned short Bs[BN * BK];   // 16 KB

    const int t = threadIdx.x;
    const int lane = t & 63, w = t >> 6;
    const int wr = w >> 1, wc = w & 1;
    const int ln15 = lane & 15, hi = lane >> 4;

    // ---- chunked-bijective XCD swizzle, y-fastest flatten
    const int gx = gridDim.x, gy = gridDim.y;
    const int nwg = gx * gy * gridDim.z;
    const int orig = blockIdx.y + gy * (blockIdx.x + gx * blockIdx.z);
    const int q = nwg >> 3, r8 = nwg & 7;
    const int xcd = orig & 7, idx = orig >> 3;
    const int wg = (xcd < r8 ? xcd * (q + 1)
                             : r8 * (q + 1) + (xcd - r8) * q) + idx;
    const int byi = wg % gy, tmpw = wg / gy;
    const int bxi = tmpw % gx, bzi = tmpw / gx;

    const int bm = byi * BM, bn = bxi * BN;

    if (CAUSAL && bn > rowBase + bm + (BM - 1)) return;   // fully-masked tile
    int Keff = K;
    if (KCAP) { int kc = rowBase + bm + BM; Keff = kc < K ? kc : K; }
    int kbeg = 0, kend = Keff;
    if (SPLITK) {
        kbeg = r64(bzi * Keff / NS);
        int ke = r64((bzi + 1) * Keff / NS);
        kend = ke < Keff ? ke : Keff;
        if (kbeg >= kend) return;          // empty slice (small Keff rows)
    }

    f32x4 acc[4][NF] = {};

    for (int k0 = kbeg; k0 < kend; k0 += BK) {
        // ---- stage both tiles (8 x global_load_lds_dwordx4 per thread)
        #pragma unroll
        for (int i = 0; i < 4; ++i) {
            int c = t + 256 * i;
            int r = c >> 3, qq = (c & 7) ^ (r & 7);       // pre-swizzled src
            GLOAD16(A + (size_t)(bm + r) * K + k0 + qq * 8, As + c * 8);
        }
        #pragma unroll
        for (int i = 0; i < 4; ++i) {
            int c = t + 256 * i;
            int r = c >> 3, qq = (c & 7) ^ (r & 7);
            GLOAD16(Bt + (size_t)(bn + r) * K + k0 + qq * 8, Bs + c * 8);
        }
        __syncthreads();                   // drains loads, publishes tile

        #pragma unroll
        for (int kk = 0; kk < 2; ++kk) {
            short8 a[4], b[NF];
            #pragma unroll
            for (int m = 0; m < 4; ++m) {
                int r = wr * 64 + m * 16 + ln15;
                int s = (kk * 4 + hi) ^ (r & 7);          // swizzled read
                a[m] = *(const short8*)(As + r * 64 + s * 8);
            }
            #pragma unroll
            for (int n = 0; n < NF; ++n) {
                int r = wc * 64 + n * 16 + ln15;
                int s = (kk * 4 + hi) ^ (r & 7);
                b[n] = *(const short8*)(Bs + r * 64 + s * 8);
            }
            __builtin_amdgcn_s_setprio(1);
            #pragma unroll
            for (int m = 0; m < 4; ++m)
                #pragma unroll
                for (int n = 0; n < NF; ++n)
                    acc[m][n] = MFMA_BF16(a[m], b[n], acc[m][n], 0, 0, 0);
            __builtin_amdgcn_s_setprio(0);
        }
        __syncthreads();                   // all waves done reading the tile
    }

    // ---- epilogue: C/D layout col = lane&15, row = (lane>>4)*4 + j
    if (OM == 5) {
        float psum[4][4];
        #pragma unroll
        for (int m = 0; m < 4; ++m)
            #pragma unroll
            for (int j = 0; j < 4; ++j) {
                int row = bm + wr * 64 + m * 16 + hi * 4 + j;
                int grow = rowBase + row;
                float s = 0.f;
                #pragma unroll
                for (int n = 0; n < NF; ++n) {
                    int col = bn + wc * 64 + n * 16 + ln15;
                    float p = (col <= grow)
                        ? __expf(acc[m][n][j] * scale) : 0.f;
                    ((unsigned short*)Cp)[(size_t)row * N + col] = f2bf(p);
                    s += p;
                }
                psum[m][j] = s;
            }
        #pragma unroll
        for (int off = 1; off < 16; off <<= 1)
            #pragma unroll
            for (int m = 0; m < 4; ++m)
                #pragma unroll
                for (int j = 0; j < 4; ++j)
                    psum[m][j] += __shfl_xor(psum[m][j], off, 64);
        if (ln15 == 0) {
            const int ci = bxi * 2 + wc;           // row-major Sp[row][128]
            #pragma unroll
            for (int m = 0; m < 4; ++m)
                #pragma unroll
                for (int j = 0; j < 4; ++j)
                    Sp[(size_t)(bm + wr * 64 + m * 16 + hi * 4 + j) * 128 + ci]
                        = psum[m][j];
        }
        return;
    }
    #pragma unroll
    for (int m = 0; m < 4; ++m)
        #pragma unroll
        for (int n = 0; n < NF; ++n)
            #pragma unroll
            for (int j = 0; j < 4; ++j) {
                int row = bm + wr * 64 + m * 16 + hi * 4 + j;
                int col = bn + wc * 64 + n * 16 + ln15;
                float v = acc[m][n][j] * scale;
                if (OM == 0)
                    ((unsigned short*)Cp)[(size_t)row * N + col] = f2bf(v);
                else if (OM == 2)
                    ((float*)Cp)[(size_t)row * N + col] = v;
                else if (OM == 3)
                    ((unsigned short*)Cp + (size_t)bzi * M * N)
                        [(size_t)row * N + col] = f2bf(v);
                else {                       // OM == 4: QKV routing
                    unsigned short* qb = (unsigned short*)Cp;
                    if (col < DIM)
                        qb[(size_t)row * DIM + col] = f2bf(v);
                    else if (col < 2 * DIM)
                        (qb + (size_t)SEQ * DIM)
                            [(size_t)row * DIM + (col - DIM)] = f2bf(v);
                    else
                        (qb + (size_t)2 * SEQ * DIM)
                            [(size_t)(col - 2 * DIM) * SEQ + row] = f2bf(v);
                }
            }
}

// ---------------------------------------------------------------------------
// Split-K reduction: cooperative rowsum from row-major Sp (128 threads/row,
// one coalesced load + shfl reduce), then sum bf16 partial slices, divide,
// SiLU, bf16 -> out (band rows). 2 rows per 256-thread block.
// ---------------------------------------------------------------------------
__global__ __launch_bounds__(256)
void reduce_silu(const unsigned short* __restrict__ part,
                 const float* __restrict__ Sp,
                 unsigned short* __restrict__ out, int ns, int rowBase)
{
    __shared__ float red[4];
    const int t = threadIdx.x, lane = t & 63, w = t >> 6;
    const size_t idx = ((size_t)blockIdx.x * 256 + t) * 8;
    const int r = (int)(idx >> 10);                 // band-local row
    int keb = rowBase + ((r >> 7) << 7) + 128;      // Keff of r's PV block-row
    if (keb > SEQ) keb = SEQ;

    // ---- cooperative rowsum: threads t>>7 pick the block's 2 rows
    {
        const int rloc = blockIdx.x * 2 + (t >> 7);
        const int seg = t & 127;
        const int nct = 2 * (((rowBase + rloc) >> 7) + 1);  // live tile-halves
        float val = (seg < nct) ? Sp[(size_t)rloc * 128 + seg] : 0.f;
        #pragma unroll
        for (int off = 1; off < 64; off <<= 1)
            val += __shfl_xor(val, off, 64);
        if (lane == 0) red[w] = val;
    }
    __syncthreads();
    const float inv = 1.0f /
        ((t < 128) ? (red[0] + red[1]) : (red[2] + red[3]));

    float s[8] = {};
    for (int z = 0; z < ns; ++z) {
        int b0 = r64(z * keb / ns);
        int b1 = r64((z + 1) * keb / ns);
        if (b1 > keb) b1 = keb;
        if (b1 > b0) {
            short8 p = *(const short8*)(part + (size_t)z * (BAND * DIM) + idx);
            #pragma unroll
            for (int j = 0; j < 8; ++j) s[j] += bf2f((unsigned short)p[j]);
        }
    }
    short8 o;
    #pragma unroll
    for (int j = 0; j < 8; ++j) {
        float v = s[j] * inv;
        o[j] = (short)f2bf(v / (1.0f + __expf(-v)));
    }
    *(short8*)(out + idx) = o;
}

// ---------------------------------------------------------------------------
__global__ __launch_bounds__(256)
void cvt_bf16(const float* __restrict__ X, unsigned short* __restrict__ Y)
{
    int i = (blockIdx.x * 256 + threadIdx.x) * 8;
    f32x4 v0 = *(const f32x4*)(X + i);
    f32x4 v1 = *(const f32x4*)(X + i + 4);
    short8 o = { (short)f2bf(v0[0]), (short)f2bf(v0[1]),
                 (short)f2bf(v0[2]), (short)f2bf(v0[3]),
                 (short)f2bf(v1[0]), (short)f2bf(v1[1]),
                 (short)f2bf(v1[2]), (short)f2bf(v1[3]) };
    *(short8*)(Y + i) = o;
}

// ---------------------------------------------------------------------------
__global__ __launch_bounds__(256)
void twT(const float* __restrict__ W, unsigned short* __restrict__ WT)
{
    __shared__ float tile[64][65];
    const int bx = blockIdx.x * 64, by = blockIdx.y * 64;
    const int t = threadIdx.x, rr = t >> 4, c4 = (t & 15) * 4;
    #pragma unroll
    for (int i = 0; i < 4; ++i) {
        int r = rr + i * 16;
        f32x4 v = *(const f32x4*)(W + (size_t)(by + r) * DIM + bx + c4);
        tile[r][c4 + 0] = v[0]; tile[r][c4 + 1] = v[1];
        tile[r][c4 + 2] = v[2]; tile[r][c4 + 3] = v[3];
    }
    __syncthreads();
    #pragma unroll
    for (int i = 0; i < 4; ++i) {
        int r = rr + i * 16;                           // WT row = bx + r
        us4 o = { f2bf(tile[c4 + 0][r]), f2bf(tile[c4 + 1][r]),
                  f2bf(tile[c4 + 2][r]), f2bf(tile[c4 + 3][r]) };
        *(us4*)(WT + (size_t)(bx + r) * DIM + by + c4) = o;
    }
}

// ---------------------------------------------------------------------------
extern "C" void kernel_launch(void* const* d_in, const int* in_sizes, int n_in,
                              void* d_out, int out_size, void* d_ws, size_t ws_size,
                              hipStream_t stream)
{
    const float* x   = (const float*)d_in[0];
    const float* wq  = (const float*)d_in[1];
    const float* wk  = (const float*)d_in[2];
    const float* wv1 = (const float*)d_in[3];
    const float* wv2 = (const float*)d_in[4];

    // ws: Q/H | K (later wv2T) | V^T | bf16 split-K partials | Sp rowsums
    const size_t E = (size_t)SEQ * DIM;              // 16 MB bf16 each
    unsigned short* qbuf  = (unsigned short*)d_ws;   // [S,D]
    unsigned short* kbuf  = qbuf + E;                // [S,D]
    unsigned short* vtbuf = kbuf + E;                // [D,S]
    unsigned short* part  = vtbuf + E;               // NS x [BAND,D] bf16
    float* Sp = (float*)(part + 4 * (size_t)BAND * DIM);  // [BAND][128] f32
    const size_t PBUF = (size_t)BAND * DIM * sizeof(unsigned short);
    int nsplit = 1;
    if (ws_size >= 3 * E * sizeof(unsigned short) + 4 * PBUF
                   + 128 * (size_t)BAND * sizeof(float)) nsplit = 4;

    // d_out (32 MB) staging: xb (16 MB) + wqT|wkT|wv1T (6 MB), then S bands.
    unsigned short* xb    = (unsigned short*)d_out;
    unsigned short* wqkv  = xb + E;                  // [3072][1024]
    unsigned short* Sband = (unsigned short*)d_out;  // [BAND][SEQ] = 32 MB

    dim3 tg(16, 16);
    cvt_bf16<<<SEQ * DIM / 2048, 256, 0, stream>>>(x, xb);
    twT<<<tg, 256, 0, stream>>>(wq,  wqkv);
    twT<<<tg, 256, 0, stream>>>(wk,  wqkv + DIM * DIM);
    twT<<<tg, 256, 0, stream>>>(wv1, wqkv + 2 * DIM * DIM);

    // Merged QKV projection: [S,1024] @ [3072,1024]^T, routed epilogue.
    gemm_bt<4,false,false,false><<<dim3(3 * DIM / 128, SEQ / 128), 256, 0, stream>>>(
        xb, wqkv, qbuf, SEQ, 3 * DIM, DIM, 1.0f, 0, 0, nullptr);

    for (int b = 0; b < 4; ++b) {
        const int rb = b * BAND;
        const int ncol = (rb + BAND) / 128;        // prune all-masked columns
        dim3 gq(ncol, BAND / 128);
        // QK^T with fused exp + row-sum partials (no separate softmax pass)
        gemm_bt<5,true,false,false><<<gq, 256, 0, stream>>>(
            qbuf + (size_t)rb * DIM, kbuf, Sband, BAND, SEQ, DIM,
            0.03125f, rb, 0, Sp);
        if (b == 3)  // K no longer needed: stage wv2^T into kbuf
            twT<<<tg, 256, 0, stream>>>(wv2, kbuf);
        dim3 gpv(DIM / 128, BAND / 128, nsplit);
        gemm_bt<3,false,true,true><<<gpv, 256, 0, stream>>>(
            Sband, vtbuf, part, BAND, DIM, SEQ, 1.0f, rb, nsplit, nullptr);
        reduce_silu<<<BAND * DIM / 2048, 256, 0, stream>>>(
            part, Sp, qbuf + (size_t)rb * DIM, nsplit, rb);
    }

    // Output projection: silu(hidden) @ wv2 -> fp32 d_out.
    gemm_bt<2,false,false,false><<<dim3(DIM / 128, SEQ / 128), 256, 0, stream>>>(
        qbuf, kbuf, d_out, SEQ, DIM, DIM, 1.0f, 0, 0, nullptr);
}

// Round 20
// 346.908 us; speedup vs baseline: 1.1596x; 1.0608x over previous
//
#include <hip/hip_runtime.h>
#include <hip/hip_bf16.h>
#include <cstdint>
#include <cstddef>

constexpr int SEQ = 8192;
constexpr int DIM = 1024;

typedef __attribute__((ext_vector_type(8))) short short8;   // bf16x8 MFMA frag
typedef __attribute__((ext_vector_type(4))) float f32x4;    // fp32x4 acc frag
typedef __attribute__((ext_vector_type(4))) unsigned short us4;

#define MFMA_BF16 __builtin_amdgcn_mfma_f32_16x16x32_bf16

static __device__ __forceinline__ unsigned short f2bf(float f) {
    uint32_t u = __builtin_bit_cast(uint32_t, f);
    u += 0x7FFFu + ((u >> 16) & 1u);      // round-to-nearest-even
    return (unsigned short)(u >> 16);
}
static __device__ __forceinline__ float bf2f(unsigned short h) {
    uint32_t u = ((uint32_t)h) << 16;
    return __builtin_bit_cast(float, u);
}
static __device__ __forceinline__ int r64(int x) {          // round to mult of 64
    return ((x + 32) >> 6) << 6;
}

#define GLOAD16(gp, lp) __builtin_amdgcn_global_load_lds(                      \
    (const __attribute__((address_space(1))) void*)(gp),                       \
    (__attribute__((address_space(3))) void*)(lp), 16, 0, 0)

// ---------------------------------------------------------------------------
// GEMM: C[M,N] = A[M,K] @ Bt[N,K]^T   (A, Bt bf16 row-major; Bt is B^T)
// BM=128, BK=64, BN=128. 256 threads = 4 waves. m97-style single-buffered
// 2-barrier K-loop — r12/r17/r19-verified optimum (762 TF; staging-bound;
// deeper pipelining neutral r10-r11; BM=256 regressed r18: fewer, bigger
// barrier groups expose stage latency — this structure needs MANY small
// independent blocks). XOR slot-swizzle (0 bank conflicts); bijective
// chunked XCD swizzle, y-fastest flatten.
// OM: 0=bf16 C[M,N]; 2=fp32 C[M,N]; 3=bf16 partial at Cp+z*M*N (split-K);
//     4=QKV-routed (col<1024 Q, <2048 K, else V^T at +2*SEQ*DIM);
//     5=QK^T fused: P=exp(masked(s*scale)) bf16 + row-sum partials
//       Sp[row*128 + bxi*2+wc] (row-major; col-major was +60us r16).
// SPLITK: even per-row split — k range [r64(z*Keff/NS), r64((z+1)*Keff/NS)).
// ---------------------------------------------------------------------------
template<int OM, bool CAUSAL, bool KCAP, bool SPLITK>
__global__ __launch_bounds__(256, 4)
void gemm_bt(const unsigned short* __restrict__ A,
             const unsigned short* __restrict__ Bt,
             void* __restrict__ Cp,
             int M, int N, int K, float scale, int rowBase, int NS,
             float* __restrict__ Sp)
{
    constexpr int BM = 128, BK = 64, BN = 128;
    constexpr int NF = BN / 32;           // 4 b-frags per wave
    __shared__ __align__(16) unsigned short As[BM * BK];   // 16 KB
    __shared__ __align__(16) unsigned short Bs[BN * BK];   // 16 KB

    const int t = threadIdx.x;
    const int lane = t & 63, w = t >> 6;
    const int wr = w >> 1, wc = w & 1;
    const int ln15 = lane & 15, hi = lane >> 4;

    // ---- chunked-bijective XCD swizzle, y-fastest flatten
    const int gx = gridDim.x, gy = gridDim.y;
    const int nwg = gx * gy * gridDim.z;
    const int orig = blockIdx.y + gy * (blockIdx.x + gx * blockIdx.z);
    const int q = nwg >> 3, r8 = nwg & 7;
    const int xcd = orig & 7, idx = orig >> 3;
    const int wg = (xcd < r8 ? xcd * (q + 1)
                             : r8 * (q + 1) + (xcd - r8) * q) + idx;
    const int byi = wg % gy, tmpw = wg / gy;
    const int bxi = tmpw % gx, bzi = tmpw / gx;

    const int bm = byi * BM, bn = bxi * BN;

    if (CAUSAL && bn > rowBase + bm + (BM - 1)) return;   // fully-masked tile
    int Keff = K;
    if (KCAP) { int kc = rowBase + bm + BM; Keff = kc < K ? kc : K; }
    int kbeg = 0, kend = Keff;
    if (SPLITK) {
        kbeg = r64(bzi * Keff / NS);
        int ke = r64((bzi + 1) * Keff / NS);
        kend = ke < Keff ? ke : Keff;
        if (kbeg >= kend) return;          // empty slice (small Keff rows)
    }

    f32x4 acc[4][NF] = {};

    for (int k0 = kbeg; k0 < kend; k0 += BK) {
        // ---- stage both tiles (8 x global_load_lds_dwordx4 per thread)
        #pragma unroll
        for (int i = 0; i < 4; ++i) {
            int c = t + 256 * i;
            int r = c >> 3, qq = (c & 7) ^ (r & 7);       // pre-swizzled src
            GLOAD16(A + (size_t)(bm + r) * K + k0 + qq * 8, As + c * 8);
        }
        #pragma unroll
        for (int i = 0; i < 4; ++i) {
            int c = t + 256 * i;
            int r = c >> 3, qq = (c & 7) ^ (r & 7);
            GLOAD16(Bt + (size_t)(bn + r) * K + k0 + qq * 8, Bs + c * 8);
        }
        __syncthreads();                   // drains loads, publishes tile

        #pragma unroll
        for (int kk = 0; kk < 2; ++kk) {
            short8 a[4], b[NF];
            #pragma unroll
            for (int m = 0; m < 4; ++m) {
                int r = wr * 64 + m * 16 + ln15;
                int s = (kk * 4 + hi) ^ (r & 7);          // swizzled read
                a[m] = *(const short8*)(As + r * 64 + s * 8);
            }
            #pragma unroll
            for (int n = 0; n < NF; ++n) {
                int r = wc * 64 + n * 16 + ln15;
                int s = (kk * 4 + hi) ^ (r & 7);
                b[n] = *(const short8*)(Bs + r * 64 + s * 8);
            }
            __builtin_amdgcn_s_setprio(1);
            #pragma unroll
            for (int m = 0; m < 4; ++m)
                #pragma unroll
                for (int n = 0; n < NF; ++n)
                    acc[m][n] = MFMA_BF16(a[m], b[n], acc[m][n], 0, 0, 0);
            __builtin_amdgcn_s_setprio(0);
        }
        __syncthreads();                   // all waves done reading the tile
    }

    // ---- epilogue: C/D layout col = lane&15, row = (lane>>4)*4 + j
    if (OM == 5) {
        float psum[4][4];
        #pragma unroll
        for (int m = 0; m < 4; ++m)
            #pragma unroll
            for (int j = 0; j < 4; ++j) {
                int row = bm + wr * 64 + m * 16 + hi * 4 + j;
                int grow = rowBase + row;
                float s = 0.f;
                #pragma unroll
                for (int n = 0; n < NF; ++n) {
                    int col = bn + wc * 64 + n * 16 + ln15;
                    float p = (col <= grow)
                        ? __expf(acc[m][n][j] * scale) : 0.f;
                    ((unsigned short*)Cp)[(size_t)row * N + col] = f2bf(p);
                    s += p;
                }
                psum[m][j] = s;
            }
        #pragma unroll
        for (int off = 1; off < 16; off <<= 1)
            #pragma unroll
            for (int m = 0; m < 4; ++m)
                #pragma unroll
                for (int j = 0; j < 4; ++j)
                    psum[m][j] += __shfl_xor(psum[m][j], off, 64);
        if (ln15 == 0) {
            const int ci = bxi * 2 + wc;           // row-major Sp[row][128]
            #pragma unroll
            for (int m = 0; m < 4; ++m)
                #pragma unroll
                for (int j = 0; j < 4; ++j)
                    Sp[(size_t)(bm + wr * 64 + m * 16 + hi * 4 + j) * 128 + ci]
                        = psum[m][j];
        }
        return;
    }
    #pragma unroll
    for (int m = 0; m < 4; ++m)
        #pragma unroll
        for (int n = 0; n < NF; ++n)
            #pragma unroll
            for (int j = 0; j < 4; ++j) {
                int row = bm + wr * 64 + m * 16 + hi * 4 + j;
                int col = bn + wc * 64 + n * 16 + ln15;
                float v = acc[m][n][j] * scale;
                if (OM == 0)
                    ((unsigned short*)Cp)[(size_t)row * N + col] = f2bf(v);
                else if (OM == 2)
                    ((float*)Cp)[(size_t)row * N + col] = v;
                else if (OM == 3)
                    ((unsigned short*)Cp + (size_t)bzi * M * N)
                        [(size_t)row * N + col] = f2bf(v);
                else {                       // OM == 4: QKV routing
                    unsigned short* qb = (unsigned short*)Cp;
                    if (col < DIM)
                        qb[(size_t)row * DIM + col] = f2bf(v);
                    else if (col < 2 * DIM)
                        (qb + (size_t)SEQ * DIM)
                            [(size_t)row * DIM + (col - DIM)] = f2bf(v);
                    else
                        (qb + (size_t)2 * SEQ * DIM)
                            [(size_t)(col - 2 * DIM) * SEQ + row] = f2bf(v);
                }
            }
}

// ---------------------------------------------------------------------------
// Split-K reduction: cooperative rowsum from row-major Sp (128 threads/row,
// one coalesced load + shfl reduce), then sum bf16 partial slices (slice
// stride bsz*DIM), divide, SiLU, bf16 -> out. 2 rows per 256-thread block.
// ---------------------------------------------------------------------------
__global__ __launch_bounds__(256)
void reduce_silu(const unsigned short* __restrict__ part,
                 const float* __restrict__ Sp,
                 unsigned short* __restrict__ out, int ns, int rowBase, int bsz)
{
    __shared__ float red[4];
    const int t = threadIdx.x, lane = t & 63, w = t >> 6;
    const size_t idx = ((size_t)blockIdx.x * 256 + t) * 8;
    const int r = (int)(idx >> 10);                 // band-local row
    int keb = rowBase + ((r >> 7) << 7) + 128;      // Keff of r's PV block-row
    if (keb > SEQ) keb = SEQ;

    // ---- cooperative rowsum: threads t>>7 pick the block's 2 rows
    {
        const int rloc = blockIdx.x * 2 + (t >> 7);
        const int seg = t & 127;
        const int nct = 2 * (((rowBase + rloc) >> 7) + 1);  // live tile-halves
        float val = (seg < nct) ? Sp[(size_t)rloc * 128 + seg] : 0.f;
        #pragma unroll
        for (int off = 1; off < 64; off <<= 1)
            val += __shfl_xor(val, off, 64);
        if (lane == 0) red[w] = val;
    }
    __syncthreads();
    const float inv = 1.0f /
        ((t < 128) ? (red[0] + red[1]) : (red[2] + red[3]));

    float s[8] = {};
    for (int z = 0; z < ns; ++z) {
        int b0 = r64(z * keb / ns);
        int b1 = r64((z + 1) * keb / ns);
        if (b1 > keb) b1 = keb;
        if (b1 > b0) {
            short8 p = *(const short8*)(part + (size_t)z * bsz * DIM + idx);
            #pragma unroll
            for (int j = 0; j < 8; ++j) s[j] += bf2f((unsigned short)p[j]);
        }
    }
    short8 o;
    #pragma unroll
    for (int j = 0; j < 8; ++j) {
        float v = s[j] * inv;
        o[j] = (short)f2bf(v / (1.0f + __expf(-v)));
    }
    *(short8*)(out + idx) = o;
}

// ---------------------------------------------------------------------------
__global__ __launch_bounds__(256)
void cvt_bf16(const float* __restrict__ X, unsigned short* __restrict__ Y)
{
    int i = (blockIdx.x * 256 + threadIdx.x) * 8;
    f32x4 v0 = *(const f32x4*)(X + i);
    f32x4 v1 = *(const f32x4*)(X + i + 4);
    short8 o = { (short)f2bf(v0[0]), (short)f2bf(v0[1]),
                 (short)f2bf(v0[2]), (short)f2bf(v0[3]),
                 (short)f2bf(v1[0]), (short)f2bf(v1[1]),
                 (short)f2bf(v1[2]), (short)f2bf(v1[3]) };
    *(short8*)(Y + i) = o;
}

// ---------------------------------------------------------------------------
// Tiled fp32 W -> bf16 W^T. twT3 does wq|wk|wv1 in one dispatch (z-indexed).
// ---------------------------------------------------------------------------
static __device__ __forceinline__ void twT_body(
    const float* __restrict__ W, unsigned short* __restrict__ WT)
{
    __shared__ float tile[64][65];
    const int bx = blockIdx.x * 64, by = blockIdx.y * 64;
    const int t = threadIdx.x, rr = t >> 4, c4 = (t & 15) * 4;
    #pragma unroll
    for (int i = 0; i < 4; ++i) {
        int r = rr + i * 16;
        f32x4 v = *(const f32x4*)(W + (size_t)(by + r) * DIM + bx + c4);
        tile[r][c4 + 0] = v[0]; tile[r][c4 + 1] = v[1];
        tile[r][c4 + 2] = v[2]; tile[r][c4 + 3] = v[3];
    }
    __syncthreads();
    #pragma unroll
    for (int i = 0; i < 4; ++i) {
        int r = rr + i * 16;                           // WT row = bx + r
        us4 o = { f2bf(tile[c4 + 0][r]), f2bf(tile[c4 + 1][r]),
                  f2bf(tile[c4 + 2][r]), f2bf(tile[c4 + 3][r]) };
        *(us4*)(WT + (size_t)(bx + r) * DIM + by + c4) = o;
    }
}

__global__ __launch_bounds__(256)
void twT(const float* __restrict__ W, unsigned short* __restrict__ WT)
{
    twT_body(W, WT);
}

__global__ __launch_bounds__(256)
void twT3(const float* __restrict__ W0, const float* __restrict__ W1,
          const float* __restrict__ W2, unsigned short* __restrict__ WT)
{
    const float* W = (blockIdx.z == 0) ? W0 : (blockIdx.z == 1) ? W1 : W2;
    twT_body(W, WT + (size_t)blockIdx.z * DIM * DIM);
}

// ---------------------------------------------------------------------------
extern "C" void kernel_launch(void* const* d_in, const int* in_sizes, int n_in,
                              void* d_out, int out_size, void* d_ws, size_t ws_size,
                              hipStream_t stream)
{
    const float* x   = (const float*)d_in[0];
    const float* wq  = (const float*)d_in[1];
    const float* wk  = (const float*)d_in[2];
    const float* wv1 = (const float*)d_in[3];
    const float* wv2 = (const float*)d_in[4];

    // ws: Q/H | K (later wv2T) | V^T | [Sband] | bf16 split-K partials | Sp
    const size_t E = (size_t)SEQ * DIM;              // 16 MB bf16 each
    unsigned short* qbuf  = (unsigned short*)d_ws;   // [S,D]
    unsigned short* kbuf  = qbuf + E;                // [S,D]
    unsigned short* vtbuf = kbuf + E;                // [D,S]
    unsigned short* wsfree = vtbuf + E;
    const size_t avail = ws_size - 3 * E * sizeof(unsigned short);

    // d_out (32 MB) staging: xb (16 MB) + wqT|wkT|wv1T (6 MB).
    unsigned short* xb    = (unsigned short*)d_out;
    unsigned short* wqkv  = xb + E;                  // [3072][1024]

    // Band config: prefer 4096-row bands with Sband in ws (L3-resident,
    // fewer serialization points); fall back to r19's 2048-in-d_out.
    int bandsz;
    unsigned short *Sband, *part;
    float* Sp;
    int nsplit = 4;
    const size_t need4096 = (size_t)4096 * SEQ * 2        // Sband 64 MB
                          + (size_t)4 * 4096 * DIM * 2    // part  32 MB
                          + (size_t)4096 * 128 * 4;       // Sp     2 MB
    if (avail >= need4096) {
        bandsz = 4096;
        Sband  = wsfree;
        part   = Sband + (size_t)4096 * SEQ;
        Sp     = (float*)(part + (size_t)4 * 4096 * DIM);
    } else {
        bandsz = 2048;
        Sband  = (unsigned short*)d_out;   // r19 layout (after proj done)
        part   = wsfree;
        Sp     = (float*)(part + (size_t)4 * 2048 * DIM);
        if (avail < (size_t)4 * 2048 * DIM * 2 + (size_t)2048 * 128 * 4)
            nsplit = 1;
    }

    cvt_bf16<<<SEQ * DIM / 2048, 256, 0, stream>>>(x, xb);
    twT3<<<dim3(16, 16, 3), 256, 0, stream>>>(wq, wk, wv1, wqkv);

    // Merged QKV projection: [S,1024] @ [3072,1024]^T, routed epilogue.
    gemm_bt<4,false,false,false><<<dim3(3 * DIM / 128, SEQ / 128), 256, 0, stream>>>(
        xb, wqkv, qbuf, SEQ, 3 * DIM, DIM, 1.0f, 0, 0, nullptr);

    for (int rb = 0; rb < SEQ; rb += bandsz) {
        const int ncol = (rb + bandsz) / 128;      // prune all-masked columns
        dim3 gq(ncol, bandsz / 128);
        // QK^T with fused exp + row-sum partials (no separate softmax pass)
        gemm_bt<5,true,false,false><<<gq, 256, 0, stream>>>(
            qbuf + (size_t)rb * DIM, kbuf, Sband, bandsz, SEQ, DIM,
            0.03125f, rb, 0, Sp);
        if (rb + bandsz == SEQ)  // K dead: stage wv2^T into kbuf
            twT<<<dim3(16, 16), 256, 0, stream>>>(wv2, kbuf);
        dim3 gpv(DIM / 128, bandsz / 128, nsplit);
        gemm_bt<3,false,true,true><<<gpv, 256, 0, stream>>>(
            Sband, vtbuf, part, bandsz, DIM, SEQ, 1.0f, rb, nsplit, nullptr);
        reduce_silu<<<bandsz * DIM / 2048, 256, 0, stream>>>(
            part, Sp, qbuf + (size_t)rb * DIM, nsplit, rb, bandsz);
    }

    // Output projection: silu(hidden) @ wv2 -> fp32 d_out.
    gemm_bt<2,false,false,false><<<dim3(DIM / 128, SEQ / 128), 256, 0, stream>>>(
        qbuf, kbuf, d_out, SEQ, DIM, DIM, 1.0f, 0, 0, nullptr);
}